// Round 8
// baseline (287.622 us; speedup 1.0000x reference)
//
#include <hip/hip_runtime.h>
#include <cmath>

#define BB 4
#define TT 2048
#define CC 1024
#define HH 16
#define DD 64
#define MM (BB*TT)   // 8192

typedef _Float16 f16x8 __attribute__((ext_vector_type(8)));
typedef _Float16 f16x4 __attribute__((ext_vector_type(4)));
typedef _Float16 f16x2 __attribute__((ext_vector_type(2)));
typedef float f32x4 __attribute__((ext_vector_type(4)));
typedef unsigned short ushort_t;

// legacy K=16 f16 MFMA: spelled WITHOUT underscore before f16 (pre-gfx950
// naming; compiler fix-it verified R7)
#define MFMA16(a,b,c) __builtin_amdgcn_mfma_f32_16x16x16f16(a,b,c,0,0,0)

__device__ __forceinline__ unsigned short f2h(float f) {
    _Float16 h = (_Float16)f;
    return __builtin_bit_cast(unsigned short, h);
}

// packed f32x2 -> f16x2 (v_cvt_pkrtz_f16_f32); builtin returns __fp16x2,
// bit-cast to our _Float16x2 (identical layout)
__device__ __forceinline__ f16x2 cvt_pk(float a, float b) {
    return __builtin_bit_cast(f16x2, __builtin_amdgcn_cvt_pkrtz(a, b));
}

// async global->LDS, 16 bytes per lane. LDS dest is WAVE-UNIFORM base;
// HW adds lane*16.
__device__ __forceinline__ void gld16(const void* gsrc, void* ldst) {
    void* g = const_cast<void*>(gsrc);
    __builtin_amdgcn_global_load_lds(
        (__attribute__((address_space(1))) void*)g,
        (__attribute__((address_space(3))) void*)ldst,
        16, 0, 0);
}

// ---------------------------------------------------------------------------
// prep: fp32 -> f16 (packed x4)
// ---------------------------------------------------------------------------
__global__ __launch_bounds__(256)
void cvt4_kernel(const float* __restrict__ in, ushort_t* __restrict__ out, long n4) {
    long i = (long)blockIdx.x * blockDim.x + threadIdx.x;
    if (i >= n4) return;
    float4 v = ((const float4*)in)[i];
    ushort4 o;
    o.x = f2h(v.x); o.y = f2h(v.y); o.z = f2h(v.z); o.w = f2h(v.w);
    ((ushort4*)out)[i] = o;
}

// ---------------------------------------------------------------------------
// prep: transpose + convert: in[K][N] fp32 -> out[N][K] f16. 32x32 tiles.
// ---------------------------------------------------------------------------
__global__ __launch_bounds__(256)
void trcvt_kernel(const float* __restrict__ in, ushort_t* __restrict__ out,
                  int K, int N) {
    __shared__ float T[32][33];
    const int tx = threadIdx.x & 31;
    const int ty = threadIdx.x >> 5;
    const int n0 = blockIdx.x * 32;
    const int k0 = blockIdx.y * 32;
    #pragma unroll
    for (int i = 0; i < 4; ++i)
        T[ty + i * 8][tx] = in[(size_t)(k0 + ty + i * 8) * N + n0 + tx];
    __syncthreads();
    #pragma unroll
    for (int i = 0; i < 4; ++i)
        out[(size_t)(n0 + ty + i * 8) * K + k0 + tx] = f2h(T[tx][ty + i * 8]);
}

// ---------------------------------------------------------------------------
// f16 MFMA GEMM, R15: counted-vmcnt pipeline with its PREREQUISITES restored.
// R14 post-mortem: pipeline was correct but neutral -- 1 block/CU (128KB LDS)
// removed m114 cross-block overlap, grid 384=1.5xCU left a 25% tail, the
// st_16x32 swizzle was null (frag reads cover whole 1024B subtiles -> already
// conflict-free), and the scattered V-store burned ~100MB of effective write
// traffic. Fixes:
//   * 3 LDS slots (safe: with one barrier/iter all reads of slot kt-1
//     complete before barrier kt -- compiler lgkmcnt waits precede the
//     barrier -- so staging kt+2 into (kt+2)%3=(kt-1)%3 is race-free).
//     GEMM1 slot 24KB x3 = 72KB -> 2 blocks/CU; GEMM2 16KB x3 = 48KB,
//     grid 512 = exactly 2/CU.
//   * no swizzle: subtile [16r x 32h], staged linearly, read whole-subtile.
//   * XCD-chunked bijective blockIdx swizzle (grids 768/512 % 8 == 0):
//     each XCD gets 8 contiguous m-rows -> A-panels L2-resident.
//   * pure-V blocks (BN=256 tile aligned to the 1024-col v range): epilogue
//     transposes through LDS [256][136] (69.6KB, reuses slots) and stores
//     coalesced 16B runs along t.
// Schedule per iter: vmcnt(NLD) [drains batch kt, leaves kt+1 in flight]
// -> raw s_barrier -> STAGE(kt+2) -> ds_read frags -> setprio(1) MFMA.
// Last iter peeled with vmcnt(0).
// ---------------------------------------------------------------------------
template<int BM, int BN, int WN, int NN, bool QKV>
__global__ __launch_bounds__(512)
void hgemm2_kernel(const ushort_t* __restrict__ A, const ushort_t* __restrict__ Bt,
                   const float* __restrict__ bias, float* __restrict__ out,
                   ushort_t* __restrict__ qh, ushort_t* __restrict__ kh,
                   ushort_t* __restrict__ vh)
{
    constexpr int K    = 1024;
    constexpr int WM   = 8 / WN;
    constexpr int MT   = BM / WM / 16;
    constexpr int NT   = BN / WN / 16;
    constexpr int LA   = BM / 128;       // A gld16 per thread per K-tile
    constexpr int LB   = BN / 128;       // B gld16 per thread per K-tile
    constexpr int NLD  = LA + LB;
    constexpr int AH   = BM * 32;        // A-slot halves
    constexpr int BH   = BN * 32;        // B-slot halves
    constexpr int SLOT = AH + BH;
    extern __shared__ ushort_t LDS[];    // 3 * SLOT halves (GEMM1 also Tr)

    const int tid  = threadIdx.x;
    const int lane = tid & 63;
    const int wid  = tid >> 6;           // 0..7
    const int wm   = wid / WN;
    const int wn   = wid % WN;
    const int lrow = lane & 15;
    const int quad = lane >> 4;

    // XCD-chunked bijective swizzle (nwg % 8 == 0)
    const int gx  = gridDim.x;
    const int nwg = gx * gridDim.y;
    int bid = blockIdx.y * gx + blockIdx.x;
    bid = (bid & 7) * (nwg >> 3) + (bid >> 3);
    const int m0 = (bid / gx) * BM;
    const int n0 = (bid % gx) * BN;

    // staging: subtile = 16 rows x 32 halves (1KB), one gld16 per wave.
    // lane L covers bytes L*16: row = L>>2, col-halves = (L&3)*8.
    const int srow  = lane >> 2;
    const int scolh = (lane & 3) * 8;
    unsigned voffA[LA], voffB[LB];
    #pragma unroll
    for (int j = 0; j < LA; ++j)
        voffA[j] = (unsigned)(m0 + (j * 8 + wid) * 16 + srow) * K + scolh;
    #pragma unroll
    for (int j = 0; j < LB; ++j)
        voffB[j] = (unsigned)(n0 + (j * 8 + wid) * 16 + srow) * K + scolh;

    f32x4 acc[MT][NT];
    const f32x4 z = {0.f, 0.f, 0.f, 0.f};
    #pragma unroll
    for (int mt = 0; mt < MT; ++mt)
        #pragma unroll
        for (int nt = 0; nt < NT; ++nt)
            acc[mt][nt] = z;

    auto STAGE = [&](int kt, int ss) {
        ushort_t* sb = &LDS[ss * SLOT];
        #pragma unroll
        for (int j = 0; j < LA; ++j)
            gld16(A + voffA[j] + kt * 32, sb + (j * 8 + wid) * 512);
        #pragma unroll
        for (int j = 0; j < LB; ++j)
            gld16(Bt + voffB[j] + kt * 32, sb + AH + (j * 8 + wid) * 512);
    };
    auto COMPUTE = [&](int cs) {
        const ushort_t* As = &LDS[cs * SLOT];
        const ushort_t* Bs = As + AH;
        f16x8 af[MT], bf[NT];
        #pragma unroll
        for (int mt = 0; mt < MT; ++mt)
            af[mt] = *(const f16x8*)&As[(wm * MT + mt) * 512 + lrow * 32 + quad * 8];
        #pragma unroll
        for (int nt = 0; nt < NT; ++nt)
            bf[nt] = *(const f16x8*)&Bs[(wn * NT + nt) * 512 + lrow * 32 + quad * 8];
        __builtin_amdgcn_s_setprio(1);
        #pragma unroll
        for (int mt = 0; mt < MT; ++mt)
            #pragma unroll
            for (int nt = 0; nt < NT; ++nt)
                acc[mt][nt] = __builtin_amdgcn_mfma_f32_16x16x32_f16(
                    af[mt], bf[nt], acc[mt][nt], 0, 0, 0);
        __builtin_amdgcn_s_setprio(0);
    };

    STAGE(0, 0);
    STAGE(1, 1);
    int cs = 0;
    for (int kt = 0; kt < 31; ++kt) {
        if constexpr (NLD == 3)
            asm volatile("s_waitcnt vmcnt(3)" ::: "memory");
        else
            asm volatile("s_waitcnt vmcnt(2)" ::: "memory");
        __builtin_amdgcn_s_barrier();
        if (kt < 30) STAGE(kt + 2, cs == 0 ? 2 : cs - 1);  // (cs+2)%3
        COMPUTE(cs);
        cs = (cs == 2) ? 0 : cs + 1;
    }
    asm volatile("s_waitcnt vmcnt(0)" ::: "memory");
    __builtin_amdgcn_s_barrier();
    COMPUTE(cs);

    if (QKV && (n0 >> 10) == 2) {
        // pure-V block: transpose through LDS, store coalesced along t.
        // Tr[256 cols][136] halves = 69.6KB (reuses slot LDS, 16B-mult rows).
        __syncthreads();                       // all waves done reading slots
        ushort_t* Tr = &LDS[0];
        #pragma unroll
        for (int mt = 0; mt < MT; ++mt) {
            const int tl = wm * (BM / WM) + mt * 16 + quad * 4;
            #pragma unroll
            for (int nt = 0; nt < NT; ++nt) {
                const int cl = wn * (BN / WN) + nt * 16 + lrow;
                const float bv = bias[n0 + cl];
                ushort4 pk;
                pk.x = f2h(acc[mt][nt][0] + bv);
                pk.y = f2h(acc[mt][nt][1] + bv);
                pk.z = f2h(acc[mt][nt][2] + bv);
                pk.w = f2h(acc[mt][nt][3] + bv);
                *(ushort4*)&Tr[cl * 136 + tl] = pk;
            }
        }
        __syncthreads();
        const int v0  = n0 & 1023;
        const int b2  = m0 >> 11;
        const int t0b = m0 & 2047;
        const int ch  = (tid & 15) * 8;        // t-chunk (8 halves, 16B)
        #pragma unroll
        for (int it = 0; it < 8; ++it) {
            const int c  = it * 32 + (tid >> 4);
            const int dg = v0 + c;
            const uint4 val = *(const uint4*)&Tr[c * 136 + ch];
            *(uint4*)&vh[(((size_t)b2 * HH + (dg >> 6)) * DD + (dg & 63)) * TT
                         + t0b + ch] = val;
        }
        return;
    }

    #pragma unroll
    for (int mt = 0; mt < MT; ++mt) {
        const int rbase = m0 + wm * (BM / WM) + mt * 16 + quad * 4;
        #pragma unroll
        for (int nt = 0; nt < NT; ++nt) {
            const int col = n0 + wn * (BN / WN) + nt * 16 + lrow;
            const float bv = bias[col];
            if (QKV) {
                const int which = col >> 10;
                const int c = col & 1023;
                const int h = c >> 6, d = c & 63;
                const int b = rbase >> 11, t0 = rbase & 2047;
                ushort_t* dst = which ? kh : qh;
                // q carries score-scale 8 and log2(e) for exp2-domain softmax
                const float sc = which ? 1.0f : 8.0f * 1.44269504088896f;
                #pragma unroll
                for (int r = 0; r < 4; ++r)
                    dst[(((size_t)b * HH + h) * TT + t0 + r) * DD + d] =
                        f2h((acc[mt][nt][r] + bv) * sc);
            } else {
                #pragma unroll
                for (int r = 0; r < 4; ++r)
                    out[(size_t)(rbase + r) * NN + col] = acc[mt][nt][r] + bv;
            }
        }
    }
}

// ---------------------------------------------------------------------------
// MFMA flash attention, R12 structure (unchanged; measured 95us, Occ 35.6,
// VALU 60, Mfma 23, zero spill): balanced-pair schedule + softmax micro-opts
// + double-buffered LDS (one barrier per iteration). Grid 16x64 = 1024 equal
// blocks, all co-resident (4/CU, LDS 36.9KB, lb(256,4)).
// ---------------------------------------------------------------------------
__global__ __launch_bounds__(256, 4)
void attn_mfma_kernel(const ushort_t* __restrict__ qh, const ushort_t* __restrict__ kh,
                      const ushort_t* __restrict__ vh, ushort_t* __restrict__ yh)
{
    __shared__ ushort_t Ks[2][64 * 72];   // [buf][key][d]
    __shared__ ushort_t Vs[2][64 * 72];   // [buf][d][key] (V transposed)

    const int pr   = blockIdx.x;          // pair index 0..15
    const int bh   = blockIdx.y;
    const int qtA  = 31 - pr;             // big tile first
    const int qtB  = pr;
    const int tid  = threadIdx.x;
    const int lane = tid & 63;
    const int w    = tid >> 6;
    const int lrow = lane & 15;
    const int quad = lane >> 4;

    const ushort_t* qbase = qh + (size_t)bh * TT * DD;
    const ushort_t* kbase = kh + (size_t)bh * TT * DD;
    const ushort_t* vbase = vh + (size_t)bh * DD * TT;
    const int b = bh >> 4, h = bh & 15;

    // staging: 256 threads x (2 K + 2 V) uint4; row ur/ur+32, 16B chunk uc
    const int ur = tid >> 3;            // 0..31
    const int uc = (tid & 7) * 8;       // halves

    int q0w = qtA * 64 + w * 16;
    f16x8 aq0 = *(const f16x8*)&qbase[(size_t)(q0w + lrow) * DD + quad * 8];
    f16x8 aq1 = *(const f16x8*)&qbase[(size_t)(q0w + lrow) * DD + 32 + quad * 8];

    const f32x4 z = {0.f, 0.f, 0.f, 0.f};
    f32x4 o[4] = {z, z, z, z};
    float mi = -1e30f, li = 0.f;

    // tile 0 regs
    uint4 kr0 = *(const uint4*)&kbase[(size_t)ur * DD + uc];
    uint4 kr1 = *(const uint4*)&kbase[(size_t)(ur + 32) * DD + uc];
    uint4 vr0 = *(const uint4*)&vbase[(size_t)ur * TT + uc];
    uint4 vr1 = *(const uint4*)&vbase[(size_t)(ur + 32) * TT + uc];

    // prologue: publish tile 0 into buf0, prefetch tile for i=1
    *(uint4*)&Ks[0][(ur)      * 72 + uc] = kr0;
    *(uint4*)&Ks[0][(ur + 32) * 72 + uc] = kr1;
    *(uint4*)&Vs[0][(ur)      * 72 + uc] = vr0;
    *(uint4*)&Vs[0][(ur + 32) * 72 + uc] = vr1;
    {
        const int nkt = (1 <= qtA) ? 1 : 0;   // i=1 -> phase A k-tile 1, or B k-tile 0
        const int nb  = nkt * 64;
        kr0 = *(const uint4*)&kbase[(size_t)(nb + ur) * DD + uc];
        kr1 = *(const uint4*)&kbase[(size_t)(nb + ur + 32) * DD + uc];
        vr0 = *(const uint4*)&vbase[(size_t)ur * TT + nb + uc];
        vr1 = *(const uint4*)&vbase[(size_t)(ur + 32) * TT + nb + uc];
    }
    __syncthreads();

    for (int i = 0; i <= 32; ++i) {
        const int cur = i & 1;
        if (i == qtA + 1) {
            // flush phase-A output; reset state for phase B
            #pragma unroll
            for (int r = 0; r < 4; ++r) {
                const float inv = 1.0f / __shfl(li, quad * 4 + r, 64);
                const int t = q0w + quad * 4 + r;
                #pragma unroll
                for (int dt = 0; dt < 4; ++dt)
                    yh[((size_t)b * TT + t) * CC + h * 64 + dt * 16 + lrow] =
                        f2h(o[dt][r] * inv);
            }
            q0w = qtB * 64 + w * 16;
            aq0 = *(const f16x8*)&qbase[(size_t)(q0w + lrow) * DD + quad * 8];
            aq1 = *(const f16x8*)&qbase[(size_t)(q0w + lrow) * DD + 32 + quad * 8];
            #pragma unroll
            for (int dt = 0; dt < 4; ++dt) o[dt] = z;
            mi = -1e30f; li = 0.f;
        }
        const int kt = (i <= qtA) ? i : i - qtA - 1;

        // S^T = K Q^T : C[row=key=quad*4+r][col=q=lrow]
        f32x4 sv[4];
        __builtin_amdgcn_s_setprio(1);
        #pragma unroll
        for (int c = 0; c < 4; ++c) {
            f16x8 ka = *(const f16x8*)&Ks[cur][(c * 16 + lrow) * 72 + quad * 8];
            f16x8 kb = *(const f16x8*)&Ks[cur][(c * 16 + lrow) * 72 + 32 + quad * 8];
            sv[c] = __builtin_amdgcn_mfma_f32_16x16x32_f16(ka, aq0, z, 0, 0, 0);
            sv[c] = __builtin_amdgcn_mfma_f32_16x16x32_f16(kb, aq1, sv[c], 0, 0, 0);
        }
        __builtin_amdgcn_s_setprio(0);

        // softmax: each lane owns q-row qg; its 16 values are keys c*16+quad*4+r
        const int kt2 = kt * 64;
        const int qg  = q0w + lrow;
        const bool diag = (i == qtA) || (i == 32);
        if (diag) {
            #pragma unroll
            for (int c = 0; c < 4; ++c)
                #pragma unroll
                for (int r = 0; r < 4; ++r)
                    if (kt2 + c * 16 + quad * 4 + r > qg) sv[c][r] = -3e38f;
        }
        // tree max (dep depth 4)
        float mc[4];
        #pragma unroll
        for (int c = 0; c < 4; ++c)
            mc[c] = fmaxf(fmaxf(sv[c][0], sv[c][1]), fmaxf(sv[c][2], sv[c][3]));
        float m = fmaxf(fmaxf(mc[0], mc[1]), fmaxf(mc[2], mc[3]));
        m = fmaxf(m, __shfl_xor(m, 16, 64));
        m = fmaxf(m, __shfl_xor(m, 32, 64));

        // defer-max (T13): only rescale when the running max grew by >8
        if (__any(m > mi + 8.0f)) {
            const float mnew  = fmaxf(mi, m);
            const float alpha = exp2f(mi - mnew);
            mi = mnew;
            li *= alpha;
            #pragma unroll
            for (int r = 0; r < 4; ++r) {
                const float ar = __shfl(alpha, quad * 4 + r, 64);
                #pragma unroll
                for (int dt = 0; dt < 4; ++dt) o[dt][r] *= ar;
            }
        }

        f16x4 ap[4];
        float rc[4];
        #pragma unroll
        for (int c = 0; c < 4; ++c) {
            const float p0 = exp2f(sv[c][0] - mi);
            const float p1 = exp2f(sv[c][1] - mi);
            const float p2 = exp2f(sv[c][2] - mi);
            const float p3 = exp2f(sv[c][3] - mi);
            rc[c] = (p0 + p1) + (p2 + p3);
            const f16x2 lo = cvt_pk(p0, p1);
            const f16x2 hi = cvt_pk(p2, p3);
            ap[c][0] = lo[0]; ap[c][1] = lo[1]; ap[c][2] = hi[0]; ap[c][3] = hi[1];
        }
        float rs = (rc[0] + rc[1]) + (rc[2] + rc[3]);
        rs += __shfl_xor(rs, 16, 64);
        rs += __shfl_xor(rs, 32, 64);
        li += rs;

        // O += P V : P^T C-layout IS the 16x16x16 A-frag (lane: q=lrow,
        // key=quad*4+j). V B-frag from Vs[d][key]: b64 per (dt,c).
        __builtin_amdgcn_s_setprio(1);
        #pragma unroll
        for (int dt = 0; dt < 4; ++dt)
            #pragma unroll
            for (int c = 0; c < 4; ++c) {
                f16x4 vb = *(const f16x4*)&Vs[cur][(dt * 16 + lrow) * 72 + c * 16 + quad * 4];
                o[dt] = MFMA16(ap[c], vb, o[dt]);
            }
        __builtin_amdgcn_s_setprio(0);

        // publish tile i+1 into the other buffer; prefetch tile i+2
        if (i < 32) {
            const int nxt = cur ^ 1;
            *(uint4*)&Ks[nxt][(ur)      * 72 + uc] = kr0;
            *(uint4*)&Ks[nxt][(ur + 32) * 72 + uc] = kr1;
            *(uint4*)&Vs[nxt][(ur)      * 72 + uc] = vr0;
            *(uint4*)&Vs[nxt][(ur + 32) * 72 + uc] = vr1;
            if (i < 31) {
                const int ni  = i + 2;
                const int nkt = (ni <= qtA) ? ni : ni - qtA - 1;
                const int nb  = nkt * 64;
                kr0 = *(const uint4*)&kbase[(size_t)(nb + ur) * DD + uc];
                kr1 = *(const uint4*)&kbase[(size_t)(nb + ur + 32) * DD + uc];
                vr0 = *(const uint4*)&vbase[(size_t)ur * TT + nb + uc];
                vr1 = *(const uint4*)&vbase[(size_t)(ur + 32) * TT + nb + uc];
            }
        }
        __syncthreads();
    }

    // final writeout (phase B)
    #pragma unroll
    for (int r = 0; r < 4; ++r) {
        const float inv = 1.0f / __shfl(li, quad * 4 + r, 64);
        const int t = q0w + quad * 4 + r;
        #pragma unroll
        for (int dt = 0; dt < 4; ++dt)
            yh[((size_t)b * TT + t) * CC + h * 64 + dt * 16 + lrow] =
                f2h(o[dt][r] * inv);
    }
}

// ---------------------------------------------------------------------------
// ws layout (halves): qh | kh | vh (8.39M each) | xh 8.39M (yh aliases xh)
//                     | wat 3.15M | wpt 1.05M     ~ 75 MB
// ---------------------------------------------------------------------------
extern "C" void kernel_launch(void* const* d_in, const int* in_sizes, int n_in,
                              void* d_out, int out_size, void* d_ws, size_t ws_size,
                              hipStream_t stream) {
    const float* x      = (const float*)d_in[0];
    const float* w_attn = (const float*)d_in[1];
    const float* b_attn = (const float*)d_in[2];
    const float* w_proj = (const float*)d_in[3];
    const float* b_proj = (const float*)d_in[4];
    float* out = (float*)d_out;

    const size_t per = (size_t)BB * HH * TT * DD;      // 8,388,608
    ushort_t* qh  = (ushort_t*)d_ws;
    ushort_t* kh  = qh + per;
    ushort_t* vh  = kh + per;
    ushort_t* xh  = vh + per;
    ushort_t* yh  = xh;                                 // alias: xh dead after GEMM1
    ushort_t* wat = xh + (size_t)MM * CC;
    ushort_t* wpt = wat + (size_t)3 * CC * CC;

    cvt4_kernel<<<(MM * CC / 4 + 255) / 256, 256, 0, stream>>>(x, xh, MM * CC / 4);
    trcvt_kernel<<<dim3(3 * CC / 32, CC / 32), 256, 0, stream>>>(w_attn, wat, CC, 3 * CC);
    trcvt_kernel<<<dim3(CC / 32, CC / 32), 256, 0, stream>>>(w_proj, wpt, CC, CC);

    // GEMM1: 128x256 tiles, grid 12 x 64 = 768 blocks (2/CU), dyn LDS 73728B
    // (3 slots x 24KB; also covers the 69.6KB V-transpose buffer)
    hgemm2_kernel<128, 256, 4, 3 * CC, true>
        <<<dim3(3 * CC / 256, MM / 128), 512, 73728, stream>>>(
        xh, wat, b_attn, nullptr, qh, kh, vh);

    // 16 balanced q-tile pairs (x) x 64 heads (y); 1024 equal blocks, 4/CU
    attn_mfma_kernel<<<dim3(16, BB * HH), 256, 0, stream>>>(qh, kh, vh, yh);

    // GEMM2: 128x128 tiles, grid 8 x 64 = 512 blocks (exactly 2/CU), 48KB
    hgemm2_kernel<128, 128, 2, CC, false>
        <<<dim3(CC / 128, MM / 128), 512, 49152, stream>>>(
        yh, wpt, b_proj, out, nullptr, nullptr, nullptr);
}

// Round 9
// 280.520 us; speedup vs baseline: 1.0253x; 1.0253x over previous
//
#include <hip/hip_runtime.h>
#include <cmath>

#define BB 4
#define TT 2048
#define CC 1024
#define HH 16
#define DD 64
#define MM (BB*TT)   // 8192

typedef _Float16 f16x8 __attribute__((ext_vector_type(8)));
typedef _Float16 f16x4 __attribute__((ext_vector_type(4)));
typedef _Float16 f16x2 __attribute__((ext_vector_type(2)));
typedef float f32x4 __attribute__((ext_vector_type(4)));
typedef unsigned short ushort_t;

// legacy K=16 f16 MFMA: spelled WITHOUT underscore before f16 (pre-gfx950
// naming; compiler fix-it verified R7)
#define MFMA16(a,b,c) __builtin_amdgcn_mfma_f32_16x16x16f16(a,b,c,0,0,0)

__device__ __forceinline__ unsigned short f2h(float f) {
    _Float16 h = (_Float16)f;
    return __builtin_bit_cast(unsigned short, h);
}

// packed f32x2 -> f16x2 (v_cvt_pkrtz_f16_f32); builtin returns __fp16x2,
// bit-cast to our _Float16x2 (identical layout)
__device__ __forceinline__ f16x2 cvt_pk(float a, float b) {
    return __builtin_bit_cast(f16x2, __builtin_amdgcn_cvt_pkrtz(a, b));
}

// async global->LDS, 16 bytes per lane (lane i -> base + i*16).
__device__ __forceinline__ void gld16(const void* gsrc, void* ldst) {
    void* g = const_cast<void*>(gsrc);
    __builtin_amdgcn_global_load_lds(
        (__attribute__((address_space(1))) void*)g,
        (__attribute__((address_space(3))) void*)ldst,
        16, 0, 0);
}

// ---------------------------------------------------------------------------
// prep: fp32 -> f16 (packed x4)
// ---------------------------------------------------------------------------
__global__ __launch_bounds__(256)
void cvt4_kernel(const float* __restrict__ in, ushort_t* __restrict__ out, long n4) {
    long i = (long)blockIdx.x * blockDim.x + threadIdx.x;
    if (i >= n4) return;
    float4 v = ((const float4*)in)[i];
    ushort4 o;
    o.x = f2h(v.x); o.y = f2h(v.y); o.z = f2h(v.z); o.w = f2h(v.w);
    ((ushort4*)out)[i] = o;
}

// ---------------------------------------------------------------------------
// prep: transpose + convert: in[K][N] fp32 -> out[N][K] f16. 32x32 tiles.
// ---------------------------------------------------------------------------
__global__ __launch_bounds__(256)
void trcvt_kernel(const float* __restrict__ in, ushort_t* __restrict__ out,
                  int K, int N) {
    __shared__ float T[32][33];
    const int tx = threadIdx.x & 31;
    const int ty = threadIdx.x >> 5;
    const int n0 = blockIdx.x * 32;
    const int k0 = blockIdx.y * 32;
    #pragma unroll
    for (int i = 0; i < 4; ++i)
        T[ty + i * 8][tx] = in[(size_t)(k0 + ty + i * 8) * N + n0 + tx];
    __syncthreads();
    #pragma unroll
    for (int i = 0; i < 4; ++i)
        out[(size_t)(n0 + ty + i * 8) * K + k0 + tx] = f2h(T[tx][ty + i * 8]);
}

// ---------------------------------------------------------------------------
// f16 MFMA GEMM, R13 version (best measured total: BK=64, two [128][32]
// sub-blocks per K-step, 32KB LDS). R14/R15 pipelined rewrites were neutral/
// regressive -- GEMM schedule surgery at K=1024 is a dead end from here.
// C[M,N] = A[M,1024] @ B[1024,N] + bias. QKV epilogue: q,k f16 [B,H,T,D];
// q pre-scaled by 8*log2(e) (exp2 softmax domain); v f16 TRANSPOSED [B,H,D,T].
// ---------------------------------------------------------------------------
template<int N, bool QKV>
__global__ __launch_bounds__(256)
void hgemm_kernel(const ushort_t* __restrict__ A, const ushort_t* __restrict__ Bt,
                  const float* __restrict__ bias, float* __restrict__ out,
                  ushort_t* __restrict__ qh, ushort_t* __restrict__ kh,
                  ushort_t* __restrict__ vh)
{
    const int K = 1024;
    __shared__ ushort_t As[2][128 * 32];   // [ks][row*32+col]
    __shared__ ushort_t Bs[2][128 * 32];

    const int tid  = threadIdx.x;
    const int lane = tid & 63;
    const int wave = tid >> 6;
    const int wm   = (wave & 1) * 64;
    const int wn   = (wave >> 1) * 64;
    const int m0   = blockIdx.y * 128;
    const int n0   = blockIdx.x * 128;
    const int lrow = lane & 15;
    const int quad = lane >> 4;

    // staging: 1024 chunks of 16B per operand tile (128 rows x 64 halves,
    // split as 2 sub-blocks of [128][32]). chunk d -> blk=d>>9,
    // row=(d>>2)&127, c16=d&3. LDS dest linear in d; global src per-lane.
    unsigned offA[4], offB[4];
    ushort_t* ldsA[4];
    ushort_t* ldsB[4];
    #pragma unroll
    for (int p = 0; p < 4; ++p) {
        const int d   = p * 256 + tid;
        const int blk = d >> 9;
        const int row = (d >> 2) & 127;
        const int c16 = d & 3;
        offA[p] = (unsigned)(m0 + row) * K + blk * 32 + c16 * 8;
        offB[p] = (unsigned)(n0 + row) * K + blk * 32 + c16 * 8;
        ldsA[p] = &As[0][0] + (p * 256 + wave * 64) * 8;
        ldsB[p] = &Bs[0][0] + (p * 256 + wave * 64) * 8;
    }

    f32x4 acc[4][4];
    const f32x4 z = {0.f, 0.f, 0.f, 0.f};
    #pragma unroll
    for (int mt = 0; mt < 4; ++mt)
        #pragma unroll
        for (int nt = 0; nt < 4; ++nt)
            acc[mt][nt] = z;

    for (int kk = 0; kk < K; kk += 64) {
        #pragma unroll
        for (int p = 0; p < 4; ++p) {
            gld16(&A[offA[p] + kk],  ldsA[p]);
            gld16(&Bt[offB[p] + kk], ldsB[p]);
        }
        __syncthreads();

        #pragma unroll
        for (int ks = 0; ks < 2; ++ks) {
            f16x8 af[4], bf[4];
            #pragma unroll
            for (int mt = 0; mt < 4; ++mt)
                af[mt] = *(const f16x8*)&As[ks][(wm + mt * 16 + lrow) * 32 + quad * 8];
            #pragma unroll
            for (int nt = 0; nt < 4; ++nt)
                bf[nt] = *(const f16x8*)&Bs[ks][(wn + nt * 16 + lrow) * 32 + quad * 8];
            #pragma unroll
            for (int mt = 0; mt < 4; ++mt)
                #pragma unroll
                for (int nt = 0; nt < 4; ++nt)
                    acc[mt][nt] = __builtin_amdgcn_mfma_f32_16x16x32_f16(
                        af[mt], bf[nt], acc[mt][nt], 0, 0, 0);
        }
        __syncthreads();
    }

    #pragma unroll
    for (int mt = 0; mt < 4; ++mt) {
        const int rbase = m0 + wm + mt * 16 + quad * 4;
        #pragma unroll
        for (int nt = 0; nt < 4; ++nt) {
            const int col = n0 + wn + nt * 16 + lrow;
            const float bv = bias[col];
            if (QKV) {
                const int which = col >> 10;
                const int c = col & 1023;
                const int h = c >> 6, d = c & 63;
                const int b = rbase >> 11, t0 = rbase & 2047;
                if (which == 2) {
                    ushort4 pk;
                    pk.x = f2h(acc[mt][nt][0] + bv);
                    pk.y = f2h(acc[mt][nt][1] + bv);
                    pk.z = f2h(acc[mt][nt][2] + bv);
                    pk.w = f2h(acc[mt][nt][3] + bv);
                    *(ushort4*)&vh[(((size_t)b * HH + h) * DD + d) * TT + t0] = pk;
                } else {
                    ushort_t* dst = which ? kh : qh;
                    // q carries score-scale 8 and log2(e) for exp2-domain softmax
                    const float sc = which ? 1.0f : 8.0f * 1.44269504088896f;
                    #pragma unroll
                    for (int r = 0; r < 4; ++r)
                        dst[(((size_t)b * HH + h) * TT + t0 + r) * DD + d] =
                            f2h((acc[mt][nt][r] + bv) * sc);
                }
            } else {
                #pragma unroll
                for (int r = 0; r < 4; ++r)
                    out[(size_t)(rbase + r) * N + col] = acc[mt][nt][r] + bv;
            }
        }
    }
}

// ---------------------------------------------------------------------------
// MFMA flash attention, R16: 128-q-row blocks. Block = 8 waves (512 thr);
// wave owns 16 q-rows; block covers a 128-row q-tile -> K/V tile staged once
// per 128 q-rows (was 64): staging/publish/prefetch/barrier cost per unit
// work HALVES; prefetch regs 16->8. Balanced pair (qtA=15-pr, qtB=pr) ->
// every block runs exactly 2(qtA+qtB)+4 = 34 iterations; grid 8x64 = 512
// blocks = exactly 2/CU = 16 waves/CU (same occupancy as R12; LDS 36.9KB x2
// = 73.7KB). lb(512,4): cap 128/wave = the proven 64arch+64acc split.
// Low waves skip their fully-masked diagonal tile (wave-uniform `active`;
// barriers/staging unaffected). Mask when kt*64+63 > q0w.
// Rest identical to R12: double-buffered LDS one-barrier loop, S^T=K*Q^T
// swapped operands, in-lane softmax + 2 shuffles, tree max/sum, defer-max
// THR=8 (exp2 domain), cvt_pk P->f16, setprio around MFMA clusters, P^T
// C-layout = PV A-frag, reg prefetch of next K/V tile.
// qh,kh: f16 [B*H][T][D]; vh: f16 [B*H][D][T]; yh: f16 [B*T][C].
// ---------------------------------------------------------------------------
__global__ __launch_bounds__(512, 4)
void attn_mfma_kernel(const ushort_t* __restrict__ qh, const ushort_t* __restrict__ kh,
                      const ushort_t* __restrict__ vh, ushort_t* __restrict__ yh)
{
    __shared__ ushort_t Ks[2][64 * 72];   // [buf][key][d]
    __shared__ ushort_t Vs[2][64 * 72];   // [buf][d][key] (V transposed)

    const int pr   = blockIdx.x;          // pair index 0..7
    const int bh   = blockIdx.y;
    const int qtA  = 15 - pr;             // big tile first (128-row q-tiles)
    const int qtB  = pr;
    const int itA  = 2 * qtA + 2;         // phase-A k-iterations
    const int tid  = threadIdx.x;
    const int lane = tid & 63;
    const int w    = tid >> 6;            // 0..7
    const int lrow = lane & 15;
    const int quad = lane >> 4;

    const ushort_t* qbase = qh + (size_t)bh * TT * DD;
    const ushort_t* kbase = kh + (size_t)bh * TT * DD;
    const ushort_t* vbase = vh + (size_t)bh * DD * TT;
    const int b = bh >> 4, h = bh & 15;

    // staging: 512 threads x (1 K + 1 V) uint4; row ur (0..63), 16B chunk uc
    const int ur = tid >> 3;              // 0..63
    const int uc = (tid & 7) * 8;         // halves

    int q0w = qtA * 128 + w * 16;
    f16x8 aq0 = *(const f16x8*)&qbase[(size_t)(q0w + lrow) * DD + quad * 8];
    f16x8 aq1 = *(const f16x8*)&qbase[(size_t)(q0w + lrow) * DD + 32 + quad * 8];

    const f32x4 z = {0.f, 0.f, 0.f, 0.f};
    f32x4 o[4] = {z, z, z, z};
    float mi = -1e30f, li = 0.f;

    // tile 0 regs
    uint4 kr = *(const uint4*)&kbase[(size_t)ur * DD + uc];
    uint4 vr = *(const uint4*)&vbase[(size_t)ur * TT + uc];

    // prologue: publish tile 0 into buf0, prefetch tile 1 (kt=1 since itA>=18)
    *(uint4*)&Ks[0][ur * 72 + uc] = kr;
    *(uint4*)&Vs[0][ur * 72 + uc] = vr;
    kr = *(const uint4*)&kbase[(size_t)(64 + ur) * DD + uc];
    vr = *(const uint4*)&vbase[(size_t)ur * TT + 64 + uc];
    __syncthreads();

    for (int i = 0; i < 34; ++i) {
        const int cur = i & 1;
        if (i == itA) {
            // flush phase-A output; reset state for phase B
            #pragma unroll
            for (int r = 0; r < 4; ++r) {
                const float inv = 1.0f / __shfl(li, quad * 4 + r, 64);
                const int t = q0w + quad * 4 + r;
                #pragma unroll
                for (int dt = 0; dt < 4; ++dt)
                    yh[((size_t)b * TT + t) * CC + h * 64 + dt * 16 + lrow] =
                        f2h(o[dt][r] * inv);
            }
            q0w = qtB * 128 + w * 16;
            aq0 = *(const f16x8*)&qbase[(size_t)(q0w + lrow) * DD + quad * 8];
            aq1 = *(const f16x8*)&qbase[(size_t)(q0w + lrow) * DD + 32 + quad * 8];
            #pragma unroll
            for (int dt = 0; dt < 4; ++dt) o[dt] = z;
            mi = -1e30f; li = 0.f;
        }
        const int kt = (i < itA) ? i : i - itA;
        const int kt2 = kt * 64;
        // wave-uniform: skip tiles fully above the causal diagonal for this
        // wave's q-rows (min qg = q0w; all keys > q0w+15 -> all-masked)
        if (kt2 <= q0w + 15) {
            // S^T = K Q^T : C[row=key=quad*4+r][col=q=lrow]
            f32x4 sv[4];
            __builtin_amdgcn_s_setprio(1);
            #pragma unroll
            for (int c = 0; c < 4; ++c) {
                f16x8 ka = *(const f16x8*)&Ks[cur][(c * 16 + lrow) * 72 + quad * 8];
                f16x8 kb = *(const f16x8*)&Ks[cur][(c * 16 + lrow) * 72 + 32 + quad * 8];
                sv[c] = __builtin_amdgcn_mfma_f32_16x16x32_f16(ka, aq0, z, 0, 0, 0);
                sv[c] = __builtin_amdgcn_mfma_f32_16x16x32_f16(kb, aq1, sv[c], 0, 0, 0);
            }
            __builtin_amdgcn_s_setprio(0);

            // softmax: lane owns q-row qg; its 16 values are keys kt2+c*16+quad*4+r
            const int qg = q0w + lrow;
            if (kt2 + 63 > q0w) {         // partial-overlap tile: causal mask
                #pragma unroll
                for (int c = 0; c < 4; ++c)
                    #pragma unroll
                    for (int r = 0; r < 4; ++r)
                        if (kt2 + c * 16 + quad * 4 + r > qg) sv[c][r] = -3e38f;
            }
            // tree max (dep depth 4)
            float mc[4];
            #pragma unroll
            for (int c = 0; c < 4; ++c)
                mc[c] = fmaxf(fmaxf(sv[c][0], sv[c][1]), fmaxf(sv[c][2], sv[c][3]));
            float m = fmaxf(fmaxf(mc[0], mc[1]), fmaxf(mc[2], mc[3]));
            m = fmaxf(m, __shfl_xor(m, 16, 64));
            m = fmaxf(m, __shfl_xor(m, 32, 64));

            // defer-max (T13): only rescale when the running max grew by >8
            if (__any(m > mi + 8.0f)) {
                const float mnew  = fmaxf(mi, m);
                const float alpha = exp2f(mi - mnew);
                mi = mnew;
                li *= alpha;
                #pragma unroll
                for (int r = 0; r < 4; ++r) {
                    const float ar = __shfl(alpha, quad * 4 + r, 64);
                    #pragma unroll
                    for (int dt = 0; dt < 4; ++dt) o[dt][r] *= ar;
                }
            }

            f16x4 ap[4];
            float rc[4];
            #pragma unroll
            for (int c = 0; c < 4; ++c) {
                const float p0 = exp2f(sv[c][0] - mi);
                const float p1 = exp2f(sv[c][1] - mi);
                const float p2 = exp2f(sv[c][2] - mi);
                const float p3 = exp2f(sv[c][3] - mi);
                rc[c] = (p0 + p1) + (p2 + p3);
                const f16x2 lo = cvt_pk(p0, p1);
                const f16x2 hi = cvt_pk(p2, p3);
                ap[c][0] = lo[0]; ap[c][1] = lo[1]; ap[c][2] = hi[0]; ap[c][3] = hi[1];
            }
            float rs = (rc[0] + rc[1]) + (rc[2] + rc[3]);
            rs += __shfl_xor(rs, 16, 64);
            rs += __shfl_xor(rs, 32, 64);
            li += rs;

            // O += P V : P^T C-layout IS the 16x16x16 A-frag (lane: q=lrow,
            // key=quad*4+j). V B-frag from Vs[d][key]: b64 per (dt,c).
            __builtin_amdgcn_s_setprio(1);
            #pragma unroll
            for (int dt = 0; dt < 4; ++dt)
                #pragma unroll
                for (int c = 0; c < 4; ++c) {
                    f16x4 vb = *(const f16x4*)&Vs[cur][(dt * 16 + lrow) * 72 + c * 16 + quad * 4];
                    o[dt] = MFMA16(ap[c], vb, o[dt]);
                }
            __builtin_amdgcn_s_setprio(0);
        }

        // publish tile i+1 into the other buffer; prefetch tile i+2
        if (i < 33) {
            const int nxt = cur ^ 1;
            *(uint4*)&Ks[nxt][ur * 72 + uc] = kr;
            *(uint4*)&Vs[nxt][ur * 72 + uc] = vr;
            if (i < 32) {
                const int ni  = i + 2;
                const int nkt = (ni < itA) ? ni : ni - itA;
                const int nb  = nkt * 64;
                kr = *(const uint4*)&kbase[(size_t)(nb + ur) * DD + uc];
                vr = *(const uint4*)&vbase[(size_t)ur * TT + nb + uc];
            }
        }
        __syncthreads();
    }

    // final writeout (phase B)
    #pragma unroll
    for (int r = 0; r < 4; ++r) {
        const float inv = 1.0f / __shfl(li, quad * 4 + r, 64);
        const int t = q0w + quad * 4 + r;
        #pragma unroll
        for (int dt = 0; dt < 4; ++dt)
            yh[((size_t)b * TT + t) * CC + h * 64 + dt * 16 + lrow] =
                f2h(o[dt][r] * inv);
    }
}

// ---------------------------------------------------------------------------
// ws layout (halves): qh | kh | vh (8.39M each) | xh 8.39M (yh aliases xh)
//                     | wat 3.15M | wpt 1.05M     ~ 75 MB
// ---------------------------------------------------------------------------
extern "C" void kernel_launch(void* const* d_in, const int* in_sizes, int n_in,
                              void* d_out, int out_size, void* d_ws, size_t ws_size,
                              hipStream_t stream) {
    const float* x      = (const float*)d_in[0];
    const float* w_attn = (const float*)d_in[1];
    const float* b_attn = (const float*)d_in[2];
    const float* w_proj = (const float*)d_in[3];
    const float* b_proj = (const float*)d_in[4];
    float* out = (float*)d_out;

    const size_t per = (size_t)BB * HH * TT * DD;      // 8,388,608
    ushort_t* qh  = (ushort_t*)d_ws;
    ushort_t* kh  = qh + per;
    ushort_t* vh  = kh + per;
    ushort_t* xh  = vh + per;
    ushort_t* yh  = xh;                                 // alias: xh dead after GEMM1
    ushort_t* wat = xh + (size_t)MM * CC;
    ushort_t* wpt = wat + (size_t)3 * CC * CC;

    cvt4_kernel<<<(MM * CC / 4 + 255) / 256, 256, 0, stream>>>(x, xh, MM * CC / 4);
    trcvt_kernel<<<dim3(3 * CC / 32, CC / 32), 256, 0, stream>>>(w_attn, wat, CC, 3 * CC);
    trcvt_kernel<<<dim3(CC / 32, CC / 32), 256, 0, stream>>>(w_proj, wpt, CC, CC);

    hgemm_kernel<3 * CC, true><<<dim3(3 * CC / 128, MM / 128), 256, 0, stream>>>(
        xh, wat, b_attn, nullptr, qh, kh, vh);

    // 8 balanced 128-row q-tile pairs (x) x 64 heads (y); 512 blocks of 8
    // waves, exactly 2/CU, all co-resident
    attn_mfma_kernel<<<dim3(8, BB * HH), 512, 0, stream>>>(qh, kh, vh, yh);

    hgemm_kernel<CC, false><<<dim3(CC / 128, MM / 128), 256, 0, stream>>>(
        yh, wpt, b_proj, out, nullptr, nullptr, nullptr);
}

// Round 10
// 270.421 us; speedup vs baseline: 1.0636x; 1.0373x over previous
//
#include <hip/hip_runtime.h>
#include <cmath>

#define BB 4
#define TT 2048
#define CC 1024
#define HH 16
#define DD 64
#define MM (BB*TT)   // 8192

typedef _Float16 f16x8 __attribute__((ext_vector_type(8)));
typedef _Float16 f16x4 __attribute__((ext_vector_type(4)));
typedef _Float16 f16x2 __attribute__((ext_vector_type(2)));
typedef float f32x4 __attribute__((ext_vector_type(4)));
typedef unsigned short ushort_t;

// legacy K=16 f16 MFMA: spelled WITHOUT underscore before f16 (pre-gfx950
// naming; compiler fix-it verified R7)
#define MFMA16(a,b,c) __builtin_amdgcn_mfma_f32_16x16x16f16(a,b,c,0,0,0)

__device__ __forceinline__ unsigned short f2h(float f) {
    _Float16 h = (_Float16)f;
    return __builtin_bit_cast(unsigned short, h);
}

// packed f32x2 -> f16x2 (v_cvt_pkrtz_f16_f32); builtin returns __fp16x2,
// bit-cast to our _Float16x2 (identical layout)
__device__ __forceinline__ f16x2 cvt_pk(float a, float b) {
    return __builtin_bit_cast(f16x2, __builtin_amdgcn_cvt_pkrtz(a, b));
}

// async global->LDS, 16 bytes per lane (lane i -> base + i*16).
__device__ __forceinline__ void gld16(const void* gsrc, void* ldst) {
    void* g = const_cast<void*>(gsrc);
    __builtin_amdgcn_global_load_lds(
        (__attribute__((address_space(1))) void*)g,
        (__attribute__((address_space(3))) void*)ldst,
        16, 0, 0);
}

// ---------------------------------------------------------------------------
// prep: fp32 -> f16 (packed x4)
// ---------------------------------------------------------------------------
__global__ __launch_bounds__(256)
void cvt4_kernel(const float* __restrict__ in, ushort_t* __restrict__ out, long n4) {
    long i = (long)blockIdx.x * blockDim.x + threadIdx.x;
    if (i >= n4) return;
    float4 v = ((const float4*)in)[i];
    ushort4 o;
    o.x = f2h(v.x); o.y = f2h(v.y); o.z = f2h(v.z); o.w = f2h(v.w);
    ((ushort4*)out)[i] = o;
}

// ---------------------------------------------------------------------------
// prep: transpose + convert BOTH weights in one launch (saves a dispatch):
// bx<96 -> w_attn [1024][3072]; else w_proj [1024][1024]. out[N][K] f16.
// ---------------------------------------------------------------------------
__global__ __launch_bounds__(256)
void trcvt2_kernel(const float* __restrict__ wa, const float* __restrict__ wp,
                   ushort_t* __restrict__ oa, ushort_t* __restrict__ op) {
    __shared__ float T[32][33];
    const int K = 1024;
    const float* in;
    ushort_t* out;
    int N, n0;
    if (blockIdx.x < 96) { in = wa; out = oa; N = 3072; n0 = blockIdx.x * 32; }
    else                 { in = wp; out = op; N = 1024; n0 = (blockIdx.x - 96) * 32; }
    const int tx = threadIdx.x & 31;
    const int ty = threadIdx.x >> 5;
    const int k0 = blockIdx.y * 32;
    #pragma unroll
    for (int i = 0; i < 4; ++i)
        T[ty + i * 8][tx] = in[(size_t)(k0 + ty + i * 8) * N + n0 + tx];
    __syncthreads();
    #pragma unroll
    for (int i = 0; i < 4; ++i)
        out[(size_t)(n0 + ty + i * 8) * K + k0 + tx] = f2h(T[tx][ty + i * 8]);
}

// ---------------------------------------------------------------------------
// f16 MFMA GEMM, R17 = R13 core (BK=64, two [128][32] sub-blocks, 32KB LDS;
// best measured) + COALESCED QKV EPILOGUE via per-wave LDS bounce.
// R0-R16 showed the core schedule is not the lever (4 structures, all ~equal)
// but the q/k scatter epilogue (64 scalar u16 stores/wave, 4x32B runs per
// instr) and 4KB-stride V stores are invariant across all of them. Each
// wave's 64t x 64col window is head-aligned: q/k target is one CONTIGUOUS
// 8KB run; v is 64 rows x 128B. After the K-loop's final barrier (all LDS
// reads retired), each wave reuses its own 8KB quarter of the 32KB LDS:
// write acc (+bias,+qscale) as [t][d] (q/k) or [d][t] (v), lgkmcnt(0), then
// 8 x dwordx4 per lane, fully coalesced. No extra barrier, no LDS growth.
// C[M,N] = A[M,1024] @ B[1024,N] + bias. q pre-scaled by 8*log2(e);
// v TRANSPOSED [B,H,D,T].
// ---------------------------------------------------------------------------
template<int N, bool QKV>
__global__ __launch_bounds__(256)
void hgemm_kernel(const ushort_t* __restrict__ A, const ushort_t* __restrict__ Bt,
                  const float* __restrict__ bias, float* __restrict__ out,
                  ushort_t* __restrict__ qh, ushort_t* __restrict__ kh,
                  ushort_t* __restrict__ vh)
{
    const int K = 1024;
    __shared__ ushort_t LDSU[16384];      // As: [0,8192) Bs: [8192,16384) halves

    const int tid  = threadIdx.x;
    const int lane = tid & 63;
    const int wave = tid >> 6;
    const int wm   = (wave & 1) * 64;
    const int wn   = (wave >> 1) * 64;
    const int m0   = blockIdx.y * 128;
    const int n0   = blockIdx.x * 128;
    const int lrow = lane & 15;
    const int quad = lane >> 4;

    // staging: 1024 chunks of 16B per operand tile (128 rows x 64 halves,
    // split as 2 sub-blocks of [128][32]). chunk d -> blk=d>>9,
    // row=(d>>2)&127, c16=d&3. LDS dest linear in d; global src per-lane.
    unsigned offA[4], offB[4];
    ushort_t* ldsA[4];
    ushort_t* ldsB[4];
    #pragma unroll
    for (int p = 0; p < 4; ++p) {
        const int d   = p * 256 + tid;
        const int blk = d >> 9;
        const int row = (d >> 2) & 127;
        const int c16 = d & 3;
        offA[p] = (unsigned)(m0 + row) * K + blk * 32 + c16 * 8;
        offB[p] = (unsigned)(n0 + row) * K + blk * 32 + c16 * 8;
        ldsA[p] = &LDSU[0]    + (p * 256 + wave * 64) * 8;
        ldsB[p] = &LDSU[8192] + (p * 256 + wave * 64) * 8;
    }

    f32x4 acc[4][4];
    const f32x4 z = {0.f, 0.f, 0.f, 0.f};
    #pragma unroll
    for (int mt = 0; mt < 4; ++mt)
        #pragma unroll
        for (int nt = 0; nt < 4; ++nt)
            acc[mt][nt] = z;

    for (int kk = 0; kk < K; kk += 64) {
        #pragma unroll
        for (int p = 0; p < 4; ++p) {
            gld16(&A[offA[p] + kk],  ldsA[p]);
            gld16(&Bt[offB[p] + kk], ldsB[p]);
        }
        __syncthreads();

        #pragma unroll
        for (int ks = 0; ks < 2; ++ks) {
            f16x8 af[4], bf[4];
            #pragma unroll
            for (int mt = 0; mt < 4; ++mt)
                af[mt] = *(const f16x8*)&LDSU[ks * 4096 + (wm + mt * 16 + lrow) * 32 + quad * 8];
            #pragma unroll
            for (int nt = 0; nt < 4; ++nt)
                bf[nt] = *(const f16x8*)&LDSU[8192 + ks * 4096 + (wn + nt * 16 + lrow) * 32 + quad * 8];
            #pragma unroll
            for (int mt = 0; mt < 4; ++mt)
                #pragma unroll
                for (int nt = 0; nt < 4; ++nt)
                    acc[mt][nt] = __builtin_amdgcn_mfma_f32_16x16x32_f16(
                        af[mt], bf[nt], acc[mt][nt], 0, 0, 0);
        }
        __syncthreads();
    }

    if (QKV) {
        // per-wave 8KB scratch (disjoint quarters; all cross-wave LDS reads
        // retired at the loop's final barrier -> no extra sync needed)
        ushort_t* scr = &LDSU[wave * 4096];      // 64 x 64 halves
        const int colw  = n0 + wn;                // wave col base (64-aligned)
        const int which = colw >> 10;
        const int hh    = (colw & 1023) >> 6;
        const int rowt  = m0 + wm;                // wave t base
        const int b2    = rowt >> 11;
        const int t0w   = rowt & 2047;
        if (which == 2) {
            // v: scratch[d][t], pack the 4 t-adjacent r's as one b64 write
            #pragma unroll
            for (int mt = 0; mt < 4; ++mt)
                #pragma unroll
                for (int nt = 0; nt < 4; ++nt) {
                    const float bv = bias[colw + nt * 16 + lrow];
                    f16x4 pk;
                    #pragma unroll
                    for (int r = 0; r < 4; ++r)
                        pk[r] = (_Float16)(acc[mt][nt][r] + bv);
                    *(f16x4*)&scr[(nt * 16 + lrow) * 64 + mt * 16 + quad * 4] = pk;
                }
            asm volatile("s_waitcnt lgkmcnt(0)" ::: "memory");
            ushort_t* base = vh + ((size_t)b2 * HH + hh) * DD * TT + t0w;
            #pragma unroll
            for (int it = 0; it < 8; ++it) {
                const int g  = it * 64 + lane;    // 16B chunk id
                const int dd = g >> 3, cc = (g & 7) * 8;
                *(uint4*)&base[(size_t)dd * TT + cc] = *(const uint4*)&scr[dd * 64 + cc];
            }
        } else {
            // q/k: scratch[t][d]; global run is CONTIGUOUS 8KB
            const float sc = which ? 1.0f : 8.0f * 1.44269504088896f;
            #pragma unroll
            for (int mt = 0; mt < 4; ++mt)
                #pragma unroll
                for (int nt = 0; nt < 4; ++nt) {
                    const float bv = bias[colw + nt * 16 + lrow];
                    #pragma unroll
                    for (int r = 0; r < 4; ++r)
                        scr[(mt * 16 + quad * 4 + r) * 64 + nt * 16 + lrow] =
                            f2h((acc[mt][nt][r] + bv) * sc);
                }
            asm volatile("s_waitcnt lgkmcnt(0)" ::: "memory");
            ushort_t* dstp = (which ? kh : qh) +
                             (((size_t)b2 * HH + hh) * TT + t0w) * DD;
            #pragma unroll
            for (int it = 0; it < 8; ++it) {
                const int g = it * 64 + lane;
                *(uint4*)&dstp[g * 8] = *(const uint4*)&scr[g * 8];
            }
        }
    } else {
        #pragma unroll
        for (int mt = 0; mt < 4; ++mt) {
            const int rbase = m0 + wm + mt * 16 + quad * 4;
            #pragma unroll
            for (int nt = 0; nt < 4; ++nt) {
                const int col = n0 + wn + nt * 16 + lrow;
                const float bv = bias[col];
                #pragma unroll
                for (int r = 0; r < 4; ++r)
                    out[(size_t)(rbase + r) * N + col] = acc[mt][nt][r] + bv;
            }
        }
    }
}

// ---------------------------------------------------------------------------
// MFMA flash attention, R16 structure (95us, best; equal to R12 but lower
// FETCH): 128-q-row blocks, 8 waves, balanced pair (qtA=15-pr, qtB=pr),
// 34 iterations, grid 8x64 = 512 blocks = exactly 2/CU. Double-buffered LDS
// one-barrier loop, S^T=K*Q^T swapped operands, in-lane softmax + 2 shuffles,
// tree max/sum, defer-max THR=8 (exp2 domain), cvt_pk P->f16, setprio,
// P^T C-layout = PV A-frag, reg prefetch of next K/V tile.
// qh,kh: f16 [B*H][T][D]; vh: f16 [B*H][D][T]; yh: f16 [B*T][C].
// ---------------------------------------------------------------------------
__global__ __launch_bounds__(512, 4)
void attn_mfma_kernel(const ushort_t* __restrict__ qh, const ushort_t* __restrict__ kh,
                      const ushort_t* __restrict__ vh, ushort_t* __restrict__ yh)
{
    __shared__ ushort_t Ks[2][64 * 72];   // [buf][key][d]
    __shared__ ushort_t Vs[2][64 * 72];   // [buf][d][key] (V transposed)

    const int pr   = blockIdx.x;          // pair index 0..7
    const int bh   = blockIdx.y;
    const int qtA  = 15 - pr;             // big tile first (128-row q-tiles)
    const int qtB  = pr;
    const int itA  = 2 * qtA + 2;         // phase-A k-iterations
    const int tid  = threadIdx.x;
    const int lane = tid & 63;
    const int w    = tid >> 6;            // 0..7
    const int lrow = lane & 15;
    const int quad = lane >> 4;

    const ushort_t* qbase = qh + (size_t)bh * TT * DD;
    const ushort_t* kbase = kh + (size_t)bh * TT * DD;
    const ushort_t* vbase = vh + (size_t)bh * DD * TT;
    const int b = bh >> 4, h = bh & 15;

    // staging: 512 threads x (1 K + 1 V) uint4; row ur (0..63), 16B chunk uc
    const int ur = tid >> 3;              // 0..63
    const int uc = (tid & 7) * 8;         // halves

    int q0w = qtA * 128 + w * 16;
    f16x8 aq0 = *(const f16x8*)&qbase[(size_t)(q0w + lrow) * DD + quad * 8];
    f16x8 aq1 = *(const f16x8*)&qbase[(size_t)(q0w + lrow) * DD + 32 + quad * 8];

    const f32x4 z = {0.f, 0.f, 0.f, 0.f};
    f32x4 o[4] = {z, z, z, z};
    float mi = -1e30f, li = 0.f;

    // tile 0 regs
    uint4 kr = *(const uint4*)&kbase[(size_t)ur * DD + uc];
    uint4 vr = *(const uint4*)&vbase[(size_t)ur * TT + uc];

    // prologue: publish tile 0 into buf0, prefetch tile 1 (kt=1 since itA>=18)
    *(uint4*)&Ks[0][ur * 72 + uc] = kr;
    *(uint4*)&Vs[0][ur * 72 + uc] = vr;
    kr = *(const uint4*)&kbase[(size_t)(64 + ur) * DD + uc];
    vr = *(const uint4*)&vbase[(size_t)ur * TT + 64 + uc];
    __syncthreads();

    for (int i = 0; i < 34; ++i) {
        const int cur = i & 1;
        if (i == itA) {
            // flush phase-A output; reset state for phase B
            #pragma unroll
            for (int r = 0; r < 4; ++r) {
                const float inv = 1.0f / __shfl(li, quad * 4 + r, 64);
                const int t = q0w + quad * 4 + r;
                #pragma unroll
                for (int dt = 0; dt < 4; ++dt)
                    yh[((size_t)b * TT + t) * CC + h * 64 + dt * 16 + lrow] =
                        f2h(o[dt][r] * inv);
            }
            q0w = qtB * 128 + w * 16;
            aq0 = *(const f16x8*)&qbase[(size_t)(q0w + lrow) * DD + quad * 8];
            aq1 = *(const f16x8*)&qbase[(size_t)(q0w + lrow) * DD + 32 + quad * 8];
            #pragma unroll
            for (int dt = 0; dt < 4; ++dt) o[dt] = z;
            mi = -1e30f; li = 0.f;
        }
        const int kt = (i < itA) ? i : i - itA;
        const int kt2 = kt * 64;
        // wave-uniform: skip tiles fully above the causal diagonal for this
        // wave's q-rows (min qg = q0w; all keys > q0w+15 -> all-masked)
        if (kt2 <= q0w + 15) {
            // S^T = K Q^T : C[row=key=quad*4+r][col=q=lrow]
            f32x4 sv[4];
            __builtin_amdgcn_s_setprio(1);
            #pragma unroll
            for (int c = 0; c < 4; ++c) {
                f16x8 ka = *(const f16x8*)&Ks[cur][(c * 16 + lrow) * 72 + quad * 8];
                f16x8 kb = *(const f16x8*)&Ks[cur][(c * 16 + lrow) * 72 + 32 + quad * 8];
                sv[c] = __builtin_amdgcn_mfma_f32_16x16x32_f16(ka, aq0, z, 0, 0, 0);
                sv[c] = __builtin_amdgcn_mfma_f32_16x16x32_f16(kb, aq1, sv[c], 0, 0, 0);
            }
            __builtin_amdgcn_s_setprio(0);

            // softmax: lane owns q-row qg; its 16 values are keys kt2+c*16+quad*4+r
            const int qg = q0w + lrow;
            if (kt2 + 63 > q0w) {         // partial-overlap tile: causal mask
                #pragma unroll
                for (int c = 0; c < 4; ++c)
                    #pragma unroll
                    for (int r = 0; r < 4; ++r)
                        if (kt2 + c * 16 + quad * 4 + r > qg) sv[c][r] = -3e38f;
            }
            // tree max (dep depth 4)
            float mc[4];
            #pragma unroll
            for (int c = 0; c < 4; ++c)
                mc[c] = fmaxf(fmaxf(sv[c][0], sv[c][1]), fmaxf(sv[c][2], sv[c][3]));
            float m = fmaxf(fmaxf(mc[0], mc[1]), fmaxf(mc[2], mc[3]));
            m = fmaxf(m, __shfl_xor(m, 16, 64));
            m = fmaxf(m, __shfl_xor(m, 32, 64));

            // defer-max (T13): only rescale when the running max grew by >8
            if (__any(m > mi + 8.0f)) {
                const float mnew  = fmaxf(mi, m);
                const float alpha = exp2f(mi - mnew);
                mi = mnew;
                li *= alpha;
                #pragma unroll
                for (int r = 0; r < 4; ++r) {
                    const float ar = __shfl(alpha, quad * 4 + r, 64);
                    #pragma unroll
                    for (int dt = 0; dt < 4; ++dt) o[dt][r] *= ar;
                }
            }

            f16x4 ap[4];
            float rc[4];
            #pragma unroll
            for (int c = 0; c < 4; ++c) {
                const float p0 = exp2f(sv[c][0] - mi);
                const float p1 = exp2f(sv[c][1] - mi);
                const float p2 = exp2f(sv[c][2] - mi);
                const float p3 = exp2f(sv[c][3] - mi);
                rc[c] = (p0 + p1) + (p2 + p3);
                const f16x2 lo = cvt_pk(p0, p1);
                const f16x2 hi = cvt_pk(p2, p3);
                ap[c][0] = lo[0]; ap[c][1] = lo[1]; ap[c][2] = hi[0]; ap[c][3] = hi[1];
            }
            float rs = (rc[0] + rc[1]) + (rc[2] + rc[3]);
            rs += __shfl_xor(rs, 16, 64);
            rs += __shfl_xor(rs, 32, 64);
            li += rs;

            // O += P V : P^T C-layout IS the 16x16x16 A-frag (lane: q=lrow,
            // key=quad*4+j). V B-frag from Vs[d][key]: b64 per (dt,c).
            __builtin_amdgcn_s_setprio(1);
            #pragma unroll
            for (int dt = 0; dt < 4; ++dt)
                #pragma unroll
                for (int c = 0; c < 4; ++c) {
                    f16x4 vb = *(const f16x4*)&Vs[cur][(dt * 16 + lrow) * 72 + c * 16 + quad * 4];
                    o[dt] = MFMA16(ap[c], vb, o[dt]);
                }
            __builtin_amdgcn_s_setprio(0);
        }

        // publish tile i+1 into the other buffer; prefetch tile i+2
        if (i < 33) {
            const int nxt = cur ^ 1;
            *(uint4*)&Ks[nxt][ur * 72 + uc] = kr;
            *(uint4*)&Vs[nxt][ur * 72 + uc] = vr;
            if (i < 32) {
                const int ni  = i + 2;
                const int nkt = (ni < itA) ? ni : ni - itA;
                const int nb  = nkt * 64;
                kr = *(const uint4*)&kbase[(size_t)(nb + ur) * DD + uc];
                vr = *(const uint4*)&vbase[(size_t)ur * TT + nb + uc];
            }
        }
        __syncthreads();
    }

    // final writeout (phase B)
    #pragma unroll
    for (int r = 0; r < 4; ++r) {
        const float inv = 1.0f / __shfl(li, quad * 4 + r, 64);
        const int t = q0w + quad * 4 + r;
        #pragma unroll
        for (int dt = 0; dt < 4; ++dt)
            yh[((size_t)b * TT + t) * CC + h * 64 + dt * 16 + lrow] =
                f2h(o[dt][r] * inv);
    }
}

// ---------------------------------------------------------------------------
// ws layout (halves): qh | kh | vh (8.39M each) | xh 8.39M (yh aliases xh)
//                     | wat 3.15M | wpt 1.05M     ~ 75 MB
// ---------------------------------------------------------------------------
extern "C" void kernel_launch(void* const* d_in, const int* in_sizes, int n_in,
                              void* d_out, int out_size, void* d_ws, size_t ws_size,
                              hipStream_t stream) {
    const float* x      = (const float*)d_in[0];
    const float* w_attn = (const float*)d_in[1];
    const float* b_attn = (const float*)d_in[2];
    const float* w_proj = (const float*)d_in[3];
    const float* b_proj = (const float*)d_in[4];
    float* out = (float*)d_out;

    const size_t per = (size_t)BB * HH * TT * DD;      // 8,388,608
    ushort_t* qh  = (ushort_t*)d_ws;
    ushort_t* kh  = qh + per;
    ushort_t* vh  = kh + per;
    ushort_t* xh  = vh + per;
    ushort_t* yh  = xh;                                 // alias: xh dead after GEMM1
    ushort_t* wat = xh + (size_t)MM * CC;
    ushort_t* wpt = wat + (size_t)3 * CC * CC;

    cvt4_kernel<<<(MM * CC / 4 + 255) / 256, 256, 0, stream>>>(x, xh, MM * CC / 4);
    // both weight transposes in one launch: bx<96 -> w_attn, else w_proj
    trcvt2_kernel<<<dim3(128, 32), 256, 0, stream>>>(w_attn, w_proj, wat, wpt);

    hgemm_kernel<3 * CC, true><<<dim3(3 * CC / 128, MM / 128), 256, 0, stream>>>(
        xh, wat, b_attn, nullptr, qh, kh, vh);

    // 8 balanced 128-row q-tile pairs (x) x 64 heads (y); 512 blocks of 8
    // waves, exactly 2/CU, all co-resident
    attn_mfma_kernel<<<dim3(8, BB * HH), 512, 0, stream>>>(qh, kh, vh, yh);

    hgemm_kernel<CC, false><<<dim3(CC / 128, MM / 128), 256, 0, stream>>>(
        yh, wpt, b_proj, out, nullptr, nullptr, nullptr);
}

// Round 11
// 269.994 us; speedup vs baseline: 1.0653x; 1.0016x over previous
//
#include <hip/hip_runtime.h>
#include <cmath>

#define BB 4
#define TT 2048
#define CC 1024
#define HH 16
#define DD 64
#define MM (BB*TT)   // 8192

typedef _Float16 f16x8 __attribute__((ext_vector_type(8)));
typedef _Float16 f16x4 __attribute__((ext_vector_type(4)));
typedef _Float16 f16x2 __attribute__((ext_vector_type(2)));
typedef float f32x4 __attribute__((ext_vector_type(4)));
typedef unsigned short ushort_t;

// legacy K=16 f16 MFMA: spelled WITHOUT underscore before f16 (pre-gfx950
// naming; compiler fix-it verified R7)
#define MFMA16(a,b,c) __builtin_amdgcn_mfma_f32_16x16x16f16(a,b,c,0,0,0)

__device__ __forceinline__ unsigned short f2h(float f) {
    _Float16 h = (_Float16)f;
    return __builtin_bit_cast(unsigned short, h);
}

// packed f32x2 -> f16x2 (v_cvt_pkrtz_f16_f32); builtin returns __fp16x2,
// bit-cast to our _Float16x2 (identical layout)
__device__ __forceinline__ f16x2 cvt_pk(float a, float b) {
    return __builtin_bit_cast(f16x2, __builtin_amdgcn_cvt_pkrtz(a, b));
}

// async global->LDS, 16 bytes per lane (lane i -> base + i*16).
__device__ __forceinline__ void gld16(const void* gsrc, void* ldst) {
    void* g = const_cast<void*>(gsrc);
    __builtin_amdgcn_global_load_lds(
        (__attribute__((address_space(1))) void*)g,
        (__attribute__((address_space(3))) void*)ldst,
        16, 0, 0);
}

// ---------------------------------------------------------------------------
// prep: fp32 -> f16 (packed x4)
// ---------------------------------------------------------------------------
__global__ __launch_bounds__(256)
void cvt4_kernel(const float* __restrict__ in, ushort_t* __restrict__ out, long n4) {
    long i = (long)blockIdx.x * blockDim.x + threadIdx.x;
    if (i >= n4) return;
    float4 v = ((const float4*)in)[i];
    ushort4 o;
    o.x = f2h(v.x); o.y = f2h(v.y); o.z = f2h(v.z); o.w = f2h(v.w);
    ((ushort4*)out)[i] = o;
}

// ---------------------------------------------------------------------------
// prep: transpose + convert BOTH weights in one launch (saves a dispatch):
// bx<96 -> w_attn [1024][3072]; else w_proj [1024][1024]. out[N][K] f16.
// ---------------------------------------------------------------------------
__global__ __launch_bounds__(256)
void trcvt2_kernel(const float* __restrict__ wa, const float* __restrict__ wp,
                   ushort_t* __restrict__ oa, ushort_t* __restrict__ op) {
    __shared__ float T[32][33];
    const int K = 1024;
    const float* in;
    ushort_t* out;
    int N, n0;
    if (blockIdx.x < 96) { in = wa; out = oa; N = 3072; n0 = blockIdx.x * 32; }
    else                 { in = wp; out = op; N = 1024; n0 = (blockIdx.x - 96) * 32; }
    const int tx = threadIdx.x & 31;
    const int ty = threadIdx.x >> 5;
    const int k0 = blockIdx.y * 32;
    #pragma unroll
    for (int i = 0; i < 4; ++i)
        T[ty + i * 8][tx] = in[(size_t)(k0 + ty + i * 8) * N + n0 + tx];
    __syncthreads();
    #pragma unroll
    for (int i = 0; i < 4; ++i)
        out[(size_t)(n0 + ty + i * 8) * K + k0 + tx] = f2h(T[tx][ty + i * 8]);
}

// ---------------------------------------------------------------------------
// f16 MFMA GEMM, R18 = R17 (BK=64 core + coalesced QKV epilogue via per-wave
// LDS bounce; -10us measured) + XCD-CHUNKED BLOCK SWIZZLE (T1).
// Memory-side budget: A re-read N/128 times, B re-read M/128 times -> ~800MB
// of L2/L3 traffic per GEMM1. Default round-robin block->XCD mapping gives
// the per-XCD 4MB L2 no panel reuse. Bijective chunked swizzle (nwg%8==0:
// 1536/512 ok): XCD x gets contiguous m-major chunk -> 8 A-panels (2MB,
// L2-resident) x all n-tiles. new = (orig%8)*(nwg/8) + orig/8.
// C[M,N] = A[M,1024] @ B[1024,N] + bias. q pre-scaled by 8*log2(e);
// v TRANSPOSED [B,H,D,T].
// ---------------------------------------------------------------------------
template<int N, bool QKV>
__global__ __launch_bounds__(256)
void hgemm_kernel(const ushort_t* __restrict__ A, const ushort_t* __restrict__ Bt,
                  const float* __restrict__ bias, float* __restrict__ out,
                  ushort_t* __restrict__ qh, ushort_t* __restrict__ kh,
                  ushort_t* __restrict__ vh)
{
    const int K = 1024;
    __shared__ ushort_t LDSU[16384];      // As: [0,8192) Bs: [8192,16384) halves

    const int tid  = threadIdx.x;
    const int lane = tid & 63;
    const int wave = tid >> 6;
    const int wm   = (wave & 1) * 64;
    const int wn   = (wave >> 1) * 64;
    const int lrow = lane & 15;
    const int quad = lane >> 4;

    // XCD-chunked bijective swizzle (m-major linear; consecutive blocks in a
    // chunk share the A-panel and walk n -> per-XCD L2 panel reuse)
    const int gx  = gridDim.x;
    const int nwg = gx * gridDim.y;
    int bid = blockIdx.y * gx + blockIdx.x;
    bid = (bid & 7) * (nwg >> 3) + (bid >> 3);
    const int m0 = (bid / gx) * 128;
    const int n0 = (bid % gx) * 128;

    // staging: 1024 chunks of 16B per operand tile (128 rows x 64 halves,
    // split as 2 sub-blocks of [128][32]). chunk d -> blk=d>>9,
    // row=(d>>2)&127, c16=d&3. LDS dest linear in d; global src per-lane.
    unsigned offA[4], offB[4];
    ushort_t* ldsA[4];
    ushort_t* ldsB[4];
    #pragma unroll
    for (int p = 0; p < 4; ++p) {
        const int d   = p * 256 + tid;
        const int blk = d >> 9;
        const int row = (d >> 2) & 127;
        const int c16 = d & 3;
        offA[p] = (unsigned)(m0 + row) * K + blk * 32 + c16 * 8;
        offB[p] = (unsigned)(n0 + row) * K + blk * 32 + c16 * 8;
        ldsA[p] = &LDSU[0]    + (p * 256 + wave * 64) * 8;
        ldsB[p] = &LDSU[8192] + (p * 256 + wave * 64) * 8;
    }

    f32x4 acc[4][4];
    const f32x4 z = {0.f, 0.f, 0.f, 0.f};
    #pragma unroll
    for (int mt = 0; mt < 4; ++mt)
        #pragma unroll
        for (int nt = 0; nt < 4; ++nt)
            acc[mt][nt] = z;

    for (int kk = 0; kk < K; kk += 64) {
        #pragma unroll
        for (int p = 0; p < 4; ++p) {
            gld16(&A[offA[p] + kk],  ldsA[p]);
            gld16(&Bt[offB[p] + kk], ldsB[p]);
        }
        __syncthreads();

        #pragma unroll
        for (int ks = 0; ks < 2; ++ks) {
            f16x8 af[4], bf[4];
            #pragma unroll
            for (int mt = 0; mt < 4; ++mt)
                af[mt] = *(const f16x8*)&LDSU[ks * 4096 + (wm + mt * 16 + lrow) * 32 + quad * 8];
            #pragma unroll
            for (int nt = 0; nt < 4; ++nt)
                bf[nt] = *(const f16x8*)&LDSU[8192 + ks * 4096 + (wn + nt * 16 + lrow) * 32 + quad * 8];
            #pragma unroll
            for (int mt = 0; mt < 4; ++mt)
                #pragma unroll
                for (int nt = 0; nt < 4; ++nt)
                    acc[mt][nt] = __builtin_amdgcn_mfma_f32_16x16x32_f16(
                        af[mt], bf[nt], acc[mt][nt], 0, 0, 0);
        }
        __syncthreads();
    }

    if (QKV) {
        // per-wave 8KB scratch (disjoint quarters; all cross-wave LDS reads
        // retired at the loop's final barrier -> no extra sync needed)
        ushort_t* scr = &LDSU[wave * 4096];      // 64 x 64 halves
        const int colw  = n0 + wn;                // wave col base (64-aligned)
        const int which = colw >> 10;
        const int hh    = (colw & 1023) >> 6;
        const int rowt  = m0 + wm;                // wave t base
        const int b2    = rowt >> 11;
        const int t0w   = rowt & 2047;
        if (which == 2) {
            // v: scratch[d][t], pack the 4 t-adjacent r's as one b64 write
            #pragma unroll
            for (int mt = 0; mt < 4; ++mt)
                #pragma unroll
                for (int nt = 0; nt < 4; ++nt) {
                    const float bv = bias[colw + nt * 16 + lrow];
                    f16x4 pk;
                    #pragma unroll
                    for (int r = 0; r < 4; ++r)
                        pk[r] = (_Float16)(acc[mt][nt][r] + bv);
                    *(f16x4*)&scr[(nt * 16 + lrow) * 64 + mt * 16 + quad * 4] = pk;
                }
            asm volatile("s_waitcnt lgkmcnt(0)" ::: "memory");
            ushort_t* base = vh + ((size_t)b2 * HH + hh) * DD * TT + t0w;
            #pragma unroll
            for (int it = 0; it < 8; ++it) {
                const int g  = it * 64 + lane;    // 16B chunk id
                const int dd = g >> 3, cc = (g & 7) * 8;
                *(uint4*)&base[(size_t)dd * TT + cc] = *(const uint4*)&scr[dd * 64 + cc];
            }
        } else {
            // q/k: scratch[t][d]; global run is CONTIGUOUS 8KB
            const float sc = which ? 1.0f : 8.0f * 1.44269504088896f;
            #pragma unroll
            for (int mt = 0; mt < 4; ++mt)
                #pragma unroll
                for (int nt = 0; nt < 4; ++nt) {
                    const float bv = bias[colw + nt * 16 + lrow];
                    #pragma unroll
                    for (int r = 0; r < 4; ++r)
                        scr[(mt * 16 + quad * 4 + r) * 64 + nt * 16 + lrow] =
                            f2h((acc[mt][nt][r] + bv) * sc);
                }
            asm volatile("s_waitcnt lgkmcnt(0)" ::: "memory");
            ushort_t* dstp = (which ? kh : qh) +
                             (((size_t)b2 * HH + hh) * TT + t0w) * DD;
            #pragma unroll
            for (int it = 0; it < 8; ++it) {
                const int g = it * 64 + lane;
                *(uint4*)&dstp[g * 8] = *(const uint4*)&scr[g * 8];
            }
        }
    } else {
        #pragma unroll
        for (int mt = 0; mt < 4; ++mt) {
            const int rbase = m0 + wm + mt * 16 + quad * 4;
            #pragma unroll
            for (int nt = 0; nt < 4; ++nt) {
                const int col = n0 + wn + nt * 16 + lrow;
                const float bv = bias[col];
                #pragma unroll
                for (int r = 0; r < 4; ++r)
                    out[(size_t)(rbase + r) * N + col] = acc[mt][nt][r] + bv;
            }
        }
    }
}

// ---------------------------------------------------------------------------
// MFMA flash attention, R16 structure (94us, best): 128-q-row blocks, 8
// waves, balanced pair (qtA=15-pr, qtB=pr), 34 iterations, grid 8x64 = 512
// blocks = exactly 2/CU. Double-buffered LDS one-barrier loop, S^T=K*Q^T
// swapped operands, in-lane softmax + 2 shuffles, tree max/sum, defer-max
// THR=8 (exp2 domain), cvt_pk P->f16, setprio, P^T C-layout = PV A-frag,
// reg prefetch of next K/V tile.
// qh,kh: f16 [B*H][T][D]; vh: f16 [B*H][D][T]; yh: f16 [B*T][C].
// ---------------------------------------------------------------------------
__global__ __launch_bounds__(512, 4)
void attn_mfma_kernel(const ushort_t* __restrict__ qh, const ushort_t* __restrict__ kh,
                      const ushort_t* __restrict__ vh, ushort_t* __restrict__ yh)
{
    __shared__ ushort_t Ks[2][64 * 72];   // [buf][key][d]
    __shared__ ushort_t Vs[2][64 * 72];   // [buf][d][key] (V transposed)

    const int pr   = blockIdx.x;          // pair index 0..7
    const int bh   = blockIdx.y;
    const int qtA  = 15 - pr;             // big tile first (128-row q-tiles)
    const int qtB  = pr;
    const int itA  = 2 * qtA + 2;         // phase-A k-iterations
    const int tid  = threadIdx.x;
    const int lane = tid & 63;
    const int w    = tid >> 6;            // 0..7
    const int lrow = lane & 15;
    const int quad = lane >> 4;

    const ushort_t* qbase = qh + (size_t)bh * TT * DD;
    const ushort_t* kbase = kh + (size_t)bh * TT * DD;
    const ushort_t* vbase = vh + (size_t)bh * DD * TT;
    const int b = bh >> 4, h = bh & 15;

    // staging: 512 threads x (1 K + 1 V) uint4; row ur (0..63), 16B chunk uc
    const int ur = tid >> 3;              // 0..63
    const int uc = (tid & 7) * 8;         // halves

    int q0w = qtA * 128 + w * 16;
    f16x8 aq0 = *(const f16x8*)&qbase[(size_t)(q0w + lrow) * DD + quad * 8];
    f16x8 aq1 = *(const f16x8*)&qbase[(size_t)(q0w + lrow) * DD + 32 + quad * 8];

    const f32x4 z = {0.f, 0.f, 0.f, 0.f};
    f32x4 o[4] = {z, z, z, z};
    float mi = -1e30f, li = 0.f;

    // tile 0 regs
    uint4 kr = *(const uint4*)&kbase[(size_t)ur * DD + uc];
    uint4 vr = *(const uint4*)&vbase[(size_t)ur * TT + uc];

    // prologue: publish tile 0 into buf0, prefetch tile 1 (kt=1 since itA>=18)
    *(uint4*)&Ks[0][ur * 72 + uc] = kr;
    *(uint4*)&Vs[0][ur * 72 + uc] = vr;
    kr = *(const uint4*)&kbase[(size_t)(64 + ur) * DD + uc];
    vr = *(const uint4*)&vbase[(size_t)ur * TT + 64 + uc];
    __syncthreads();

    for (int i = 0; i < 34; ++i) {
        const int cur = i & 1;
        if (i == itA) {
            // flush phase-A output; reset state for phase B
            #pragma unroll
            for (int r = 0; r < 4; ++r) {
                const float inv = 1.0f / __shfl(li, quad * 4 + r, 64);
                const int t = q0w + quad * 4 + r;
                #pragma unroll
                for (int dt = 0; dt < 4; ++dt)
                    yh[((size_t)b * TT + t) * CC + h * 64 + dt * 16 + lrow] =
                        f2h(o[dt][r] * inv);
            }
            q0w = qtB * 128 + w * 16;
            aq0 = *(const f16x8*)&qbase[(size_t)(q0w + lrow) * DD + quad * 8];
            aq1 = *(const f16x8*)&qbase[(size_t)(q0w + lrow) * DD + 32 + quad * 8];
            #pragma unroll
            for (int dt = 0; dt < 4; ++dt) o[dt] = z;
            mi = -1e30f; li = 0.f;
        }
        const int kt = (i < itA) ? i : i - itA;
        const int kt2 = kt * 64;
        // wave-uniform: skip tiles fully above the causal diagonal for this
        // wave's q-rows (min qg = q0w; all keys > q0w+15 -> all-masked)
        if (kt2 <= q0w + 15) {
            // S^T = K Q^T : C[row=key=quad*4+r][col=q=lrow]
            f32x4 sv[4];
            __builtin_amdgcn_s_setprio(1);
            #pragma unroll
            for (int c = 0; c < 4; ++c) {
                f16x8 ka = *(const f16x8*)&Ks[cur][(c * 16 + lrow) * 72 + quad * 8];
                f16x8 kb = *(const f16x8*)&Ks[cur][(c * 16 + lrow) * 72 + 32 + quad * 8];
                sv[c] = __builtin_amdgcn_mfma_f32_16x16x32_f16(ka, aq0, z, 0, 0, 0);
                sv[c] = __builtin_amdgcn_mfma_f32_16x16x32_f16(kb, aq1, sv[c], 0, 0, 0);
            }
            __builtin_amdgcn_s_setprio(0);

            // softmax: lane owns q-row qg; its 16 values are keys kt2+c*16+quad*4+r
            const int qg = q0w + lrow;
            if (kt2 + 63 > q0w) {         // partial-overlap tile: causal mask
                #pragma unroll
                for (int c = 0; c < 4; ++c)
                    #pragma unroll
                    for (int r = 0; r < 4; ++r)
                        if (kt2 + c * 16 + quad * 4 + r > qg) sv[c][r] = -3e38f;
            }
            // tree max (dep depth 4)
            float mc[4];
            #pragma unroll
            for (int c = 0; c < 4; ++c)
                mc[c] = fmaxf(fmaxf(sv[c][0], sv[c][1]), fmaxf(sv[c][2], sv[c][3]));
            float m = fmaxf(fmaxf(mc[0], mc[1]), fmaxf(mc[2], mc[3]));
            m = fmaxf(m, __shfl_xor(m, 16, 64));
            m = fmaxf(m, __shfl_xor(m, 32, 64));

            // defer-max (T13): only rescale when the running max grew by >8
            if (__any(m > mi + 8.0f)) {
                const float mnew  = fmaxf(mi, m);
                const float alpha = exp2f(mi - mnew);
                mi = mnew;
                li *= alpha;
                #pragma unroll
                for (int r = 0; r < 4; ++r) {
                    const float ar = __shfl(alpha, quad * 4 + r, 64);
                    #pragma unroll
                    for (int dt = 0; dt < 4; ++dt) o[dt][r] *= ar;
                }
            }

            f16x4 ap[4];
            float rc[4];
            #pragma unroll
            for (int c = 0; c < 4; ++c) {
                const float p0 = exp2f(sv[c][0] - mi);
                const float p1 = exp2f(sv[c][1] - mi);
                const float p2 = exp2f(sv[c][2] - mi);
                const float p3 = exp2f(sv[c][3] - mi);
                rc[c] = (p0 + p1) + (p2 + p3);
                const f16x2 lo = cvt_pk(p0, p1);
                const f16x2 hi = cvt_pk(p2, p3);
                ap[c][0] = lo[0]; ap[c][1] = lo[1]; ap[c][2] = hi[0]; ap[c][3] = hi[1];
            }
            float rs = (rc[0] + rc[1]) + (rc[2] + rc[3]);
            rs += __shfl_xor(rs, 16, 64);
            rs += __shfl_xor(rs, 32, 64);
            li += rs;

            // O += P V : P^T C-layout IS the 16x16x16 A-frag (lane: q=lrow,
            // key=quad*4+j). V B-frag from Vs[d][key]: b64 per (dt,c).
            __builtin_amdgcn_s_setprio(1);
            #pragma unroll
            for (int dt = 0; dt < 4; ++dt)
                #pragma unroll
                for (int c = 0; c < 4; ++c) {
                    f16x4 vb = *(const f16x4*)&Vs[cur][(dt * 16 + lrow) * 72 + c * 16 + quad * 4];
                    o[dt] = MFMA16(ap[c], vb, o[dt]);
                }
            __builtin_amdgcn_s_setprio(0);
        }

        // publish tile i+1 into the other buffer; prefetch tile i+2
        if (i < 33) {
            const int nxt = cur ^ 1;
            *(uint4*)&Ks[nxt][ur * 72 + uc] = kr;
            *(uint4*)&Vs[nxt][ur * 72 + uc] = vr;
            if (i < 32) {
                const int ni  = i + 2;
                const int nkt = (ni < itA) ? ni : ni - itA;
                const int nb  = nkt * 64;
                kr = *(const uint4*)&kbase[(size_t)(nb + ur) * DD + uc];
                vr = *(const uint4*)&vbase[(size_t)ur * TT + nb + uc];
            }
        }
        __syncthreads();
    }

    // final writeout (phase B)
    #pragma unroll
    for (int r = 0; r < 4; ++r) {
        const float inv = 1.0f / __shfl(li, quad * 4 + r, 64);
        const int t = q0w + quad * 4 + r;
        #pragma unroll
        for (int dt = 0; dt < 4; ++dt)
            yh[((size_t)b * TT + t) * CC + h * 64 + dt * 16 + lrow] =
                f2h(o[dt][r] * inv);
    }
}

// ---------------------------------------------------------------------------
// ws layout (halves): qh | kh | vh (8.39M each) | xh 8.39M (yh aliases xh)
//                     | wat 3.15M | wpt 1.05M     ~ 75 MB
// ---------------------------------------------------------------------------
extern "C" void kernel_launch(void* const* d_in, const int* in_sizes, int n_in,
                              void* d_out, int out_size, void* d_ws, size_t ws_size,
                              hipStream_t stream) {
    const float* x      = (const float*)d_in[0];
    const float* w_attn = (const float*)d_in[1];
    const float* b_attn = (const float*)d_in[2];
    const float* w_proj = (const float*)d_in[3];
    const float* b_proj = (const float*)d_in[4];
    float* out = (float*)d_out;

    const size_t per = (size_t)BB * HH * TT * DD;      // 8,388,608
    ushort_t* qh  = (ushort_t*)d_ws;
    ushort_t* kh  = qh + per;
    ushort_t* vh  = kh + per;
    ushort_t* xh  = vh + per;
    ushort_t* yh  = xh;                                 // alias: xh dead after GEMM1
    ushort_t* wat = xh + (size_t)MM * CC;
    ushort_t* wpt = wat + (size_t)3 * CC * CC;

    cvt4_kernel<<<(MM * CC / 4 + 255) / 256, 256, 0, stream>>>(x, xh, MM * CC / 4);
    // both weight transposes in one launch: bx<96 -> w_attn, else w_proj
    trcvt2_kernel<<<dim3(128, 32), 256, 0, stream>>>(w_attn, w_proj, wat, wpt);

    hgemm_kernel<3 * CC, true><<<dim3(3 * CC / 128, MM / 128), 256, 0, stream>>>(
        xh, wat, b_attn, nullptr, qh, kh, vh);

    // 8 balanced 128-row q-tile pairs (x) x 64 heads (y); 512 blocks of 8
    // waves, exactly 2/CU, all co-resident
    attn_mfma_kernel<<<dim3(8, BB * HH), 512, 0, stream>>>(qh, kh, vh, yh);

    hgemm_kernel<CC, false><<<dim3(CC / 128, MM / 128), 256, 0, stream>>>(
        yh, wpt, b_proj, out, nullptr, nullptr, nullptr);
}